// Round 10
// baseline (64.437 us; speedup 1.0000x reference)
//
#include <hip/hip_runtime.h>
#include <math.h>

#define PI_HALF 1.57079632679489662f

typedef float v2f __attribute__((ext_vector_type(2)));
typedef _Float16 h8 __attribute__((ext_vector_type(8)));
typedef _Float16 h2v __attribute__((ext_vector_type(2)));
typedef float f4 __attribute__((ext_vector_type(4)));

// ---------------------------------------------------------------------------
// R10 = R9 algorithm (precompute unitary U as fp16 B-matrix, MFMA GEMM with
// fused z-epilogue) with the schedule fixed:
//  - MFMA loop kt-outer / t-inner: 8 independent accumulator chains share one
//    A ds_read; L2 latency of B loads hides under sibling chains.
//  - 256-thread blocks (4 waves), 16 samples/block, 1024 blocks.
//  - LDS aliased across phases: A_lds(8.4K) + R1(2.8K) + R2(4.4K) ~= 15.6KB.
// ---------------------------------------------------------------------------

__device__ __forceinline__ v2f sp(float x) { v2f r; r.x = x; r.y = x; return r; }
__device__ __forceinline__ v2f pkfma(v2f a, v2f b, v2f c) {
  return __builtin_elementwise_fma(a, b, c);
}

template <int CTRL>
__device__ __forceinline__ float dpp_mov(float v) {
  int r = __builtin_amdgcn_update_dpp(0, __float_as_int(v), CTRL, 0xf, 0xf, true);
  return __int_as_float(r);
}
template <int CTRL, int ROW, int BANK>
__device__ __forceinline__ float mdpp(float old_, float src) {
  int r = __builtin_amdgcn_update_dpp(__float_as_int(old_), __float_as_int(src),
                                      CTRL, ROW, BANK, false);
  return __int_as_float(r);
}
template <int MASK>  // xor within 16-lane rows, MASK in {1,2,4,8}
__device__ __forceinline__ float lane_xor(float v) {
  if constexpr (MASK == 1) return dpp_mov<0xB1>(v);
  else if constexpr (MASK == 2) return dpp_mov<0x4E>(v);
  else if constexpr (MASK == 8) return dpp_mov<0x128>(v);
  else return dpp_mov<0x1B>(dpp_mov<0x141>(v));
}
template <int MASK>
__device__ __forceinline__ v2f dpp2(v2f v) {
  v2f r; r.x = lane_xor<MASK>(v.x); r.y = lane_xor<MASK>(v.y); return r;
}

// --- circuit pieces (verbatim from R7/R9, verified) ---
template <int W>
__device__ __forceinline__ void rot_lane(v2f (&RE)[8], v2f (&IM)[8],
                                         const float4 mA, int g) {
  constexpr int LM = 1 << (3 - W);
  const unsigned bit = (g >> (3 - W)) & 1u;
  const int sgn = (int)(bit << 31);
  v2f Av = sp(mA.x);
  v2f Bv = sp(__int_as_float(__float_as_int(mA.y) ^ sgn));
  v2f Cv = sp(__int_as_float(__float_as_int(mA.z) ^ sgn));
  v2f Dv = sp(mA.w);
#pragma unroll
  for (int j = 0; j < 8; ++j) {
    v2f pr = dpp2<LM>(RE[j]);
    v2f pi = dpp2<LM>(IM[j]);
    v2f nr = pkfma(-Dv, pi, pkfma(Cv, pr, pkfma(-Bv, IM[j], Av * RE[j])));
    v2f ni = pkfma( Dv, pr, pkfma(Cv, pi, pkfma( Bv, RE[j], Av * IM[j])));
    RE[j] = nr; IM[j] = ni;
  }
}
template <int JM>
__device__ __forceinline__ void rot_regj(v2f (&RE)[8], v2f (&IM)[8],
                                         const float4 mA) {
  v2f M0r = sp(mA.x), M0i = sp(mA.y), M1r = sp(mA.z), M1i = sp(mA.w);
#pragma unroll
  for (int j = 0; j < 8; ++j) {
    if (!(j & JM)) {
      const int j1 = j | JM;
      v2f r0 = RE[j], i0 = IM[j], r1 = RE[j1], i1 = IM[j1];
      RE[j]  = pkfma(-M1i, i1, pkfma(M1r, r1, pkfma(-M0i, i0, M0r * r0)));
      IM[j]  = pkfma( M1i, r1, pkfma(M1r, i1, pkfma( M0i, r0, M0r * i0)));
      RE[j1] = pkfma( M0i, i1, pkfma(M0r, r1, pkfma(-M1i, i0, (-M1r) * r0)));
      IM[j1] = pkfma(-M0i, r1, pkfma(M0r, i1, pkfma( M1i, r0, (-M1r) * i0)));
    }
  }
}
__device__ __forceinline__ void rot_regh(v2f (&RE)[8], v2f (&IM)[8],
                                         const float4 mA) {
#pragma unroll
  for (int j = 0; j < 8; ++j) {
    float r0 = RE[j].x, i0 = IM[j].x, r1 = RE[j].y, i1 = IM[j].y;
    RE[j].x = fmaf(-mA.w, i1, fmaf(mA.z, r1, fmaf(-mA.y, i0, mA.x * r0)));
    IM[j].x = fmaf( mA.w, r1, fmaf(mA.z, i1, fmaf( mA.y, r0, mA.x * i0)));
    RE[j].y = fmaf( mA.y, i1, fmaf(mA.x, r1, fmaf(-mA.w, i0, -mA.z * r0)));
    IM[j].y = fmaf(-mA.y, r1, fmaf(mA.x, i1, fmaf( mA.w, r0, -mA.z * i0)));
  }
}
template <int GPOS, int LM>
__device__ __forceinline__ void cnot_LL(v2f (&RE)[8], v2f (&IM)[8], int g) {
  if constexpr (GPOS >= 2) {
    constexpr int BANK = (GPOS == 3) ? 0xC : 0xA;
    if constexpr (LM == 4) {
#pragma unroll
      for (int j = 0; j < 8; ++j) {
        float t0 = dpp_mov<0x141>(RE[j].x);
        float t1 = dpp_mov<0x141>(RE[j].y);
        float t2 = dpp_mov<0x141>(IM[j].x);
        float t3 = dpp_mov<0x141>(IM[j].y);
        RE[j].x = mdpp<0x1B, 0xF, BANK>(RE[j].x, t0);
        RE[j].y = mdpp<0x1B, 0xF, BANK>(RE[j].y, t1);
        IM[j].x = mdpp<0x1B, 0xF, BANK>(IM[j].x, t2);
        IM[j].y = mdpp<0x1B, 0xF, BANK>(IM[j].y, t3);
      }
    } else {
      constexpr int CTRL = (LM == 1) ? 0xB1 : (LM == 2) ? 0x4E : 0x128;
#pragma unroll
      for (int j = 0; j < 8; ++j) {
        RE[j].x = mdpp<CTRL, 0xF, BANK>(RE[j].x, RE[j].x);
        RE[j].y = mdpp<CTRL, 0xF, BANK>(RE[j].y, RE[j].y);
        IM[j].x = mdpp<CTRL, 0xF, BANK>(IM[j].x, IM[j].x);
        IM[j].y = mdpp<CTRL, 0xF, BANK>(IM[j].y, IM[j].y);
      }
    }
  } else {
    constexpr int CTRL =
        (GPOS == 1 && LM == 1) ? 0xB4 :
        (GPOS == 1 && LM == 2) ? 0x44 :
        (GPOS == 0 && LM == 1) ? 0xA0 :
                                 0x6C;
#pragma unroll
    for (int j = 0; j < 8; ++j) {
      RE[j].x = dpp_mov<CTRL>(RE[j].x);
      RE[j].y = dpp_mov<CTRL>(RE[j].y);
      IM[j].x = dpp_mov<CTRL>(IM[j].x);
      IM[j].y = dpp_mov<CTRL>(IM[j].y);
    }
  }
}
template <int GPOS, int JM>
__device__ __forceinline__ void cnot_LR(v2f (&RE)[8], v2f (&IM)[8], int g) {
  const bool cb = (g >> GPOS) & 1;
#pragma unroll
  for (int j = 0; j < 8; ++j) {
    if (!(j & JM)) {
      const int j1 = j | JM;
      v2f r0 = RE[j], r1 = RE[j1];
      RE[j] = cb ? r1 : r0;  RE[j1] = cb ? r0 : r1;
      v2f i0 = IM[j], i1 = IM[j1];
      IM[j] = cb ? i1 : i0;  IM[j1] = cb ? i0 : i1;
    }
  }
}
template <int GPOS>
__device__ __forceinline__ void cnot_LH(v2f (&RE)[8], v2f (&IM)[8], int g) {
  const bool cb = (g >> GPOS) & 1;
#pragma unroll
  for (int j = 0; j < 8; ++j) {
    v2f r = RE[j]; v2f rs; rs.x = r.y; rs.y = r.x;
    RE[j] = cb ? rs : r;
    v2f i = IM[j]; v2f is2; is2.x = i.y; is2.y = i.x;
    IM[j] = cb ? is2 : i;
  }
}
template <int JC, int LM>
__device__ __forceinline__ void cnot_RL(v2f (&RE)[8], v2f (&IM)[8]) {
#pragma unroll
  for (int j = 0; j < 8; ++j) {
    if (j & JC) {
      RE[j] = dpp2<LM>(RE[j]);
      IM[j] = dpp2<LM>(IM[j]);
    }
  }
}
template <int JC>
__device__ __forceinline__ void cnot_RH(v2f (&RE)[8], v2f (&IM)[8]) {
#pragma unroll
  for (int j = 0; j < 8; ++j) {
    if (j & JC) {
      v2f r = RE[j]; RE[j].x = r.y; RE[j].y = r.x;
      v2f i = IM[j]; IM[j].x = i.y; IM[j].y = i.x;
    }
  }
}
template <int LM>
__device__ __forceinline__ void cnot_HL(v2f (&RE)[8], v2f (&IM)[8]) {
#pragma unroll
  for (int j = 0; j < 8; ++j) {
    RE[j].y = lane_xor<LM>(RE[j].y);
    IM[j].y = lane_xor<LM>(IM[j].y);
  }
}
template <int JC, int JT>
__device__ __forceinline__ void cnot_RR(v2f (&RE)[8], v2f (&IM)[8]) {
#pragma unroll
  for (int j = 0; j < 8; ++j) {
    if ((j & JC) && !(j & JT)) {
      const int j1 = j | JT;
      v2f t = RE[j]; RE[j] = RE[j1]; RE[j1] = t;
      t = IM[j]; IM[j] = IM[j1]; IM[j1] = t;
    }
  }
}

__device__ __forceinline__ void stage_fence() { __threadfence_block(); }

#define CIRCUIT_BODY(RE, IM, g)                                        \
  ROTS(0)                                                              \
  cnot_LL<3, 4>(RE, IM, g);  cnot_LL<2, 2>(RE, IM, g);                 \
  cnot_LL<1, 1>(RE, IM, g);  cnot_LR<0, 4>(RE, IM, g);                 \
  cnot_RR<4, 2>(RE, IM);     cnot_RR<2, 1>(RE, IM);                    \
  cnot_RH<1>(RE, IM);        cnot_HL<8>(RE, IM);                       \
  ROTS(1)                                                              \
  cnot_LL<3, 2>(RE, IM, g);  cnot_LL<2, 1>(RE, IM, g);                 \
  cnot_LR<1, 4>(RE, IM, g);  cnot_LR<0, 2>(RE, IM, g);                 \
  cnot_RR<4, 1>(RE, IM);     cnot_RH<2>(RE, IM);                       \
  cnot_RL<1, 8>(RE, IM);     cnot_HL<4>(RE, IM);                       \
  ROTS(2)                                                              \
  cnot_LL<3, 1>(RE, IM, g);  cnot_LR<2, 4>(RE, IM, g);                 \
  cnot_LR<1, 2>(RE, IM, g);  cnot_LR<0, 1>(RE, IM, g);                 \
  cnot_RH<4>(RE, IM);        cnot_RL<2, 8>(RE, IM);                    \
  cnot_RL<1, 4>(RE, IM);     cnot_HL<2>(RE, IM);                       \
  ROTS(3)                                                              \
  cnot_LR<3, 4>(RE, IM, g);  cnot_LR<2, 2>(RE, IM, g);                 \
  cnot_LR<1, 1>(RE, IM, g);  cnot_LH<0>(RE, IM, g);                    \
  cnot_RL<4, 8>(RE, IM);     cnot_RL<2, 4>(RE, IM);                    \
  cnot_RL<1, 2>(RE, IM);     cnot_HL<1>(RE, IM);

// ===========================================================================
// Kernel 1: build U columns -> B[512][256] fp16 in workspace (R9, verified).
// ===========================================================================
__global__ __launch_bounds__(256) void build_u_kernel(
    const float* __restrict__ qw, _Float16* __restrict__ Bt) {
  __shared__ __align__(16) float rotm[32][4];
  const int tid = threadIdx.x;
  const int g = tid & 15;
  const int ls = tid >> 4;
  const int c = blockIdx.x * 16 + ls;

  if (tid < 32) {
    float phi = qw[tid * 3 + 0];
    float th  = qw[tid * 3 + 1];
    float om  = qw[tid * 3 + 2];
    float st_, ct; sincosf(0.5f * th, &st_, &ct);
    float sa, ca;  sincosf(0.5f * (phi + om), &sa, &ca);
    float sb, cb;  sincosf(0.5f * (phi - om), &sb, &cb);
    rotm[tid][0] =  ca * ct;
    rotm[tid][1] = -sa * ct;
    rotm[tid][2] = -cb * st_;
    rotm[tid][3] = -sb * st_;
  }
  __syncthreads();

  v2f RE[8], IM[8];
#pragma unroll
  for (int j = 0; j < 8; ++j) {
    RE[j].x = (c == g * 16 + 2 * j)     ? 1.0f : 0.0f;
    RE[j].y = (c == g * 16 + 2 * j + 1) ? 1.0f : 0.0f;
    IM[j] = sp(0.0f);
  }

#define RM(L, W) (*(const float4*)(&rotm[(L) * 8 + (W)][0]))
#define ROTS(L)                                                          \
  {                                                                      \
    float4 c0 = RM(L, 0), c1 = RM(L, 1), c2 = RM(L, 2), c3 = RM(L, 3),   \
           c4 = RM(L, 4), c5 = RM(L, 5), c6 = RM(L, 6), c7 = RM(L, 7);   \
    rot_lane<0>(RE, IM, c0, g);                                          \
    rot_lane<1>(RE, IM, c1, g);                                          \
    rot_lane<2>(RE, IM, c2, g);                                          \
    rot_lane<3>(RE, IM, c3, g);                                          \
    rot_regj<4>(RE, IM, c4);                                             \
    rot_regj<2>(RE, IM, c5);                                             \
    rot_regj<1>(RE, IM, c6);                                             \
    rot_regh(RE, IM, c7);                                                \
  }
  CIRCUIT_BODY(RE, IM, g)
#undef ROTS
#undef RM

#pragma unroll
  for (int j = 0; j < 8; ++j) {
    const int i0 = g * 16 + 2 * j;
    Bt[i0 * 256 + c]             = (_Float16)RE[j].x;
    Bt[(i0 + 1) * 256 + c]       = (_Float16)RE[j].y;
    Bt[(256 + i0) * 256 + c]     = (_Float16)IM[j].x;
    Bt[(256 + i0 + 1) * 256 + c] = (_Float16)IM[j].y;
  }
}

// ===========================================================================
// Kernel 2: 256 threads (4 waves), 16 samples/block, 1024 blocks.
// ===========================================================================
__global__ __launch_bounds__(256) void hqc_main(
    const float* __restrict__ x,
    const float* __restrict__ w1, const float* __restrict__ b1,
    const float* __restrict__ w2, const float* __restrict__ b2,
    const float* __restrict__ w3, const float* __restrict__ b3,
    const _Float16* __restrict__ Bt,
    const float* __restrict__ wp1, const float* __restrict__ bp1,
    const float* __restrict__ wp2, const float* __restrict__ bp2,
    const float* __restrict__ wp3, const float* __restrict__ bp3,
    float* __restrict__ out, int B) {
  __shared__ __align__(16) _Float16 A_lds[16][264];  // psi_in fp16
  __shared__ __align__(16) float R1[16][44];  // x -> h2 -> z -> p2
  __shared__ __align__(16) float R2[16][68];  // h1 -> q -> p1

  const int tid = threadIdx.x;
  const int g = tid & 15;
  const int ls = tid >> 4;          // 0..15 sample slot
  const int s = blockIdx.x * 16 + ls;
  const bool valid = (s < B);

  // --- stage x -> R1 ---
  if (valid) {
    R1[ls][g]      = x[s * 41 + g];
    R1[ls][g + 16] = x[s * 41 + g + 16];
    if (g < 9) R1[ls][g + 32] = x[s * 41 + g + 32];
  }
  stage_fence();

  // --- pre layer1: 41 -> 64 (packed) -> R2 ---
  {
    const float4* w1v = (const float4*)w1;
    float4 bv = ((const float4*)b1)[g];
    v2f aA; aA.x = bv.x; aA.y = bv.y;
    v2f aB; aB.x = bv.z; aB.y = bv.w;
#pragma unroll 8
    for (int k = 0; k < 41; ++k) {
      float xk = R1[ls][k];
      float4 wv = w1v[k * 16 + g];
      v2f w01; w01.x = wv.x; w01.y = wv.y;
      v2f w23; w23.x = wv.z; w23.y = wv.w;
      v2f xv = sp(xk);
      aA = pkfma(xv, w01, aA);
      aB = pkfma(xv, w23, aB);
    }
    float4 st4;
    st4.x = fmaxf(aA.x, 0.f); st4.y = fmaxf(aA.y, 0.f);
    st4.z = fmaxf(aB.x, 0.f); st4.w = fmaxf(aB.y, 0.f);
    *(float4*)(&R2[ls][4 * g]) = st4;
  }
  stage_fence();

  // --- layer2: 64 -> 32 (packed) -> R1 (x dead) ---
  {
    const v2f* w2v = (const v2f*)w2;
    v2f a2 = ((const v2f*)b2)[g];
#pragma unroll 8
    for (int k = 0; k < 64; ++k)
      a2 = pkfma(sp(R2[ls][k]), w2v[k * 16 + g], a2);
    R1[ls][2 * g]     = fmaxf(a2.x, 0.f);
    R1[ls][2 * g + 1] = fmaxf(a2.y, 0.f);
  }
  stage_fence();

  // --- layer3: 32 -> 8, tanh, RY -> R2 (h1 dead) ---
  if (g < 8) {
    float acc = b3[g];
#pragma unroll
    for (int k = 0; k < 32; ++k) acc = fmaf(R1[ls][k], w3[k * 8 + g], acc);
    float q = tanhf(acc);
    float sh, ch; sincosf(q * PI_HALF, &sh, &ch);
    R2[ls][g]     = ch;
    R2[ls][8 + g] = sh;
  }
  stage_fence();

  // --- psi_in product state (real) -> A_lds fp16 ---
  {
    float cwv[8], swv[8];
#pragma unroll
    for (int w = 0; w < 8; ++w) { cwv[w] = R2[ls][w]; swv[w] = R2[ls][8 + w]; }
    float lp = 1.0f;
#pragma unroll
    for (int w = 0; w < 4; ++w) lp *= ((g >> (3 - w)) & 1) ? swv[w] : cwv[w];
    float f45[4];
#pragma unroll
    for (int a = 0; a < 4; ++a)
      f45[a] = ((a & 2) ? swv[4] : cwv[4]) * ((a & 1) ? swv[5] : cwv[5]);
    v2f F67[2];
    F67[0].x = cwv[6] * cwv[7]; F67[0].y = cwv[6] * swv[7];
    F67[1].x = swv[6] * cwv[7]; F67[1].y = swv[6] * swv[7];
#pragma unroll
    for (int j = 0; j < 8; ++j) {
      v2f amp = sp(lp * f45[j >> 1]) * F67[j & 1];
      h2v pk; pk.x = (_Float16)amp.x; pk.y = (_Float16)amp.y;
      *(h2v*)(&A_lds[ls][g * 16 + 2 * j]) = pk;  // 4B aligned store
    }
  }
  __syncthreads();

  // --- MFMA phase: kt-outer, 8 independent acc chains ---
  {
    const int l = tid & 63;
    const int w = tid >> 6;        // wave = pgrp 0..3
    const int cN = l & 15;
    const int rgrp = l >> 4;       // 0..3
    const int kb = rgrp * 8;

    f4 accr[4], acci[4];
#pragma unroll
    for (int t = 0; t < 4; ++t) {
      accr[t] = (f4){0.f, 0.f, 0.f, 0.f};
      acci[t] = (f4){0.f, 0.f, 0.f, 0.f};
    }
    const _Float16* Arow = &A_lds[cN][kb];
    const _Float16* Bre[4];
    const _Float16* Bim[4];
#pragma unroll
    for (int t = 0; t < 4; ++t) {
      const int p = w + 4 * t;
      Bre[t] = Bt + (p * 16 + cN) * 256 + kb;
      Bim[t] = Bt + ((256 + p * 16) + cN) * 256 + kb;
    }

#pragma unroll
    for (int kt = 0; kt < 8; ++kt) {
      h8 av = *(const h8*)(Arow + kt * 32);
      h8 br0 = *(const h8*)(Bre[0] + kt * 32);
      h8 bi0 = *(const h8*)(Bim[0] + kt * 32);
      h8 br1 = *(const h8*)(Bre[1] + kt * 32);
      h8 bi1 = *(const h8*)(Bim[1] + kt * 32);
      h8 br2 = *(const h8*)(Bre[2] + kt * 32);
      h8 bi2 = *(const h8*)(Bim[2] + kt * 32);
      h8 br3 = *(const h8*)(Bre[3] + kt * 32);
      h8 bi3 = *(const h8*)(Bim[3] + kt * 32);
      accr[0] = __builtin_amdgcn_mfma_f32_16x16x32_f16(av, br0, accr[0], 0, 0, 0);
      acci[0] = __builtin_amdgcn_mfma_f32_16x16x32_f16(av, bi0, acci[0], 0, 0, 0);
      accr[1] = __builtin_amdgcn_mfma_f32_16x16x32_f16(av, br1, accr[1], 0, 0, 0);
      acci[1] = __builtin_amdgcn_mfma_f32_16x16x32_f16(av, bi1, acci[1], 0, 0, 0);
      accr[2] = __builtin_amdgcn_mfma_f32_16x16x32_f16(av, br2, accr[2], 0, 0, 0);
      acci[2] = __builtin_amdgcn_mfma_f32_16x16x32_f16(av, bi2, acci[2], 0, 0, 0);
      accr[3] = __builtin_amdgcn_mfma_f32_16x16x32_f16(av, br3, accr[3], 0, 0, 0);
      acci[3] = __builtin_amdgcn_mfma_f32_16x16x32_f16(av, bi3, acci[3], 0, 0, 0);
    }

    // z-epilogue: zlo = wires 0-3 (p bits), zhi = wires 4-7 (cN bits)
    float4 zlo[4], zhi[4];
#pragma unroll
    for (int v = 0; v < 4; ++v) {
      zlo[v] = make_float4(0.f, 0.f, 0.f, 0.f);
      zhi[v] = make_float4(0.f, 0.f, 0.f, 0.f);
    }
    const float4 csgn = make_float4((cN & 8) ? -1.f : 1.f, (cN & 4) ? -1.f : 1.f,
                                    (cN & 2) ? -1.f : 1.f, (cN & 1) ? -1.f : 1.f);
#pragma unroll
    for (int t = 0; t < 4; ++t) {
      const int p = w + 4 * t;
      const float4 psgn = make_float4((p & 8) ? -1.f : 1.f, (p & 4) ? -1.f : 1.f,
                                      (p & 2) ? -1.f : 1.f, (p & 1) ? -1.f : 1.f);
#pragma unroll
      for (int v = 0; v < 4; ++v) {
        float tot = fmaf(accr[t][v], accr[t][v], acci[t][v] * acci[t][v]);
        zlo[v].x = fmaf(tot, psgn.x, zlo[v].x);
        zlo[v].y = fmaf(tot, psgn.y, zlo[v].y);
        zlo[v].z = fmaf(tot, psgn.z, zlo[v].z);
        zlo[v].w = fmaf(tot, psgn.w, zlo[v].w);
        zhi[v].x = fmaf(tot, csgn.x, zhi[v].x);
        zhi[v].y = fmaf(tot, csgn.y, zhi[v].y);
        zhi[v].z = fmaf(tot, csgn.z, zhi[v].z);
        zhi[v].w = fmaf(tot, csgn.w, zhi[v].w);
      }
    }

#define RED(M)                                                            \
  _Pragma("unroll")                                                       \
  for (int v = 0; v < 4; ++v) {                                           \
    zlo[v].x += lane_xor<M>(zlo[v].x); zlo[v].y += lane_xor<M>(zlo[v].y); \
    zlo[v].z += lane_xor<M>(zlo[v].z); zlo[v].w += lane_xor<M>(zlo[v].w); \
    zhi[v].x += lane_xor<M>(zhi[v].x); zhi[v].y += lane_xor<M>(zhi[v].y); \
    zhi[v].z += lane_xor<M>(zhi[v].z); zhi[v].w += lane_xor<M>(zhi[v].w); \
  }
    RED(1) RED(2) RED(4) RED(8)
#undef RED

    if (cN == 0) {
#pragma unroll
      for (int v = 0; v < 4; ++v) {
        const int smp = rgrp * 4 + v;
        *(float4*)&R1[smp][w * 8]     = zlo[v];
        *(float4*)&R1[smp][w * 8 + 4] = zhi[v];
      }
    }
  }
  __syncthreads();

  // --- post-MLP ---
  float zp[8];
#pragma unroll
  for (int k = 0; k < 8; ++k)
    zp[k] = (R1[ls][k] + R1[ls][8 + k]) + (R1[ls][16 + k] + R1[ls][24 + k]);

  {
    const v2f* wp1v = (const v2f*)wp1;
    v2f q1 = ((const v2f*)bp1)[g];
#pragma unroll
    for (int k = 0; k < 8; ++k)
      q1 = pkfma(sp(zp[k]), wp1v[k * 16 + g], q1);
    R2[ls][2 * g]     = fmaxf(q1.x, 0.f);
    R2[ls][2 * g + 1] = fmaxf(q1.y, 0.f);
  }
  stage_fence();

  {
    float q2 = bp2[g];
#pragma unroll
    for (int k = 0; k < 32; ++k) q2 = fmaf(R2[ls][k], wp2[k * 16 + g], q2);
    R1[ls][g] = fmaxf(q2, 0.f);
  }
  stage_fence();

  if (g < 5 && valid) {
    float o = bp3[g];
#pragma unroll
    for (int k = 0; k < 16; ++k) o = fmaf(R1[ls][k], wp3[k * 5 + g], o);
    out[s * 5 + g] = o;
  }
}

extern "C" void kernel_launch(void* const* d_in, const int* in_sizes, int n_in,
                              void* d_out, int out_size, void* d_ws,
                              size_t ws_size, hipStream_t stream) {
  const float* x   = (const float*)d_in[0];
  const float* w1  = (const float*)d_in[1];
  const float* b1  = (const float*)d_in[2];
  const float* w2  = (const float*)d_in[3];
  const float* b2  = (const float*)d_in[4];
  const float* w3  = (const float*)d_in[5];
  const float* b3  = (const float*)d_in[6];
  const float* qw  = (const float*)d_in[7];
  const float* wp1 = (const float*)d_in[8];
  const float* bp1 = (const float*)d_in[9];
  const float* wp2 = (const float*)d_in[10];
  const float* bp2 = (const float*)d_in[11];
  const float* wp3 = (const float*)d_in[12];
  const float* bp3 = (const float*)d_in[13];
  float* out = (float*)d_out;
  _Float16* Bt = (_Float16*)d_ws;  // 256 KiB
  const int B = in_sizes[0] / 41;

  hipLaunchKernelGGL(build_u_kernel, dim3(16), dim3(256), 0, stream, qw, Bt);

  const int blocks = (B + 15) / 16;
  hipLaunchKernelGGL(hqc_main, dim3(blocks), dim3(256), 0, stream,
                     x, w1, b1, w2, b2, w3, b3, Bt,
                     wp1, bp1, wp2, bp2, wp3, bp3, out, B);
}

// Round 11
// 44.970 us; speedup vs baseline: 1.4329x; 1.4329x over previous
//
#include <hip/hip_runtime.h>
#include <math.h>

#define PI_HALF 1.57079632679489662f

typedef float v2f __attribute__((ext_vector_type(2)));
typedef _Float16 h8 __attribute__((ext_vector_type(8)));
typedef _Float16 h2v __attribute__((ext_vector_type(2)));
typedef float f4 __attribute__((ext_vector_type(4)));

// ---------------------------------------------------------------------------
// R11 = R10 with BOTH GEMM operands stored in MFMA-fragment order:
//   Btf[((p*2+part)*8+kt)*512 + l*8 + e]  (fp16, 256 KiB in d_ws)
//   -> wave B-load = base + l*8 halves: 64 lanes x 16B CONSECUTIVE (1 txn,
//      was 16 scattered cache lines -> the R9/R10 latency disaster).
//   A (psi) in LDS flat fragment order: ds_read at kt*1024 + l*16 bytes,
//   stride-1 lanes, conflict-free.
// Element (i,k): p=i>>4, cN=i&15, kt=k>>5, rgrp=(k>>3)&3, e=k&7, l=rgrp*16+cN.
// ---------------------------------------------------------------------------

__device__ __forceinline__ v2f sp(float x) { v2f r; r.x = x; r.y = x; return r; }
__device__ __forceinline__ v2f pkfma(v2f a, v2f b, v2f c) {
  return __builtin_elementwise_fma(a, b, c);
}

template <int CTRL>
__device__ __forceinline__ float dpp_mov(float v) {
  int r = __builtin_amdgcn_update_dpp(0, __float_as_int(v), CTRL, 0xf, 0xf, true);
  return __int_as_float(r);
}
template <int CTRL, int ROW, int BANK>
__device__ __forceinline__ float mdpp(float old_, float src) {
  int r = __builtin_amdgcn_update_dpp(__float_as_int(old_), __float_as_int(src),
                                      CTRL, ROW, BANK, false);
  return __int_as_float(r);
}
template <int MASK>  // xor within 16-lane rows, MASK in {1,2,4,8}
__device__ __forceinline__ float lane_xor(float v) {
  if constexpr (MASK == 1) return dpp_mov<0xB1>(v);
  else if constexpr (MASK == 2) return dpp_mov<0x4E>(v);
  else if constexpr (MASK == 8) return dpp_mov<0x128>(v);
  else return dpp_mov<0x1B>(dpp_mov<0x141>(v));
}
template <int MASK>
__device__ __forceinline__ v2f dpp2(v2f v) {
  v2f r; r.x = lane_xor<MASK>(v.x); r.y = lane_xor<MASK>(v.y); return r;
}

// --- circuit pieces (verbatim, verified R7/R9/R10) ---
template <int W>
__device__ __forceinline__ void rot_lane(v2f (&RE)[8], v2f (&IM)[8],
                                         const float4 mA, int g) {
  constexpr int LM = 1 << (3 - W);
  const unsigned bit = (g >> (3 - W)) & 1u;
  const int sgn = (int)(bit << 31);
  v2f Av = sp(mA.x);
  v2f Bv = sp(__int_as_float(__float_as_int(mA.y) ^ sgn));
  v2f Cv = sp(__int_as_float(__float_as_int(mA.z) ^ sgn));
  v2f Dv = sp(mA.w);
#pragma unroll
  for (int j = 0; j < 8; ++j) {
    v2f pr = dpp2<LM>(RE[j]);
    v2f pi = dpp2<LM>(IM[j]);
    v2f nr = pkfma(-Dv, pi, pkfma(Cv, pr, pkfma(-Bv, IM[j], Av * RE[j])));
    v2f ni = pkfma( Dv, pr, pkfma(Cv, pi, pkfma( Bv, RE[j], Av * IM[j])));
    RE[j] = nr; IM[j] = ni;
  }
}
template <int JM>
__device__ __forceinline__ void rot_regj(v2f (&RE)[8], v2f (&IM)[8],
                                         const float4 mA) {
  v2f M0r = sp(mA.x), M0i = sp(mA.y), M1r = sp(mA.z), M1i = sp(mA.w);
#pragma unroll
  for (int j = 0; j < 8; ++j) {
    if (!(j & JM)) {
      const int j1 = j | JM;
      v2f r0 = RE[j], i0 = IM[j], r1 = RE[j1], i1 = IM[j1];
      RE[j]  = pkfma(-M1i, i1, pkfma(M1r, r1, pkfma(-M0i, i0, M0r * r0)));
      IM[j]  = pkfma( M1i, r1, pkfma(M1r, i1, pkfma( M0i, r0, M0r * i0)));
      RE[j1] = pkfma( M0i, i1, pkfma(M0r, r1, pkfma(-M1i, i0, (-M1r) * r0)));
      IM[j1] = pkfma(-M0i, r1, pkfma(M0r, i1, pkfma( M1i, r0, (-M1r) * i0)));
    }
  }
}
__device__ __forceinline__ void rot_regh(v2f (&RE)[8], v2f (&IM)[8],
                                         const float4 mA) {
#pragma unroll
  for (int j = 0; j < 8; ++j) {
    float r0 = RE[j].x, i0 = IM[j].x, r1 = RE[j].y, i1 = IM[j].y;
    RE[j].x = fmaf(-mA.w, i1, fmaf(mA.z, r1, fmaf(-mA.y, i0, mA.x * r0)));
    IM[j].x = fmaf( mA.w, r1, fmaf(mA.z, i1, fmaf( mA.y, r0, mA.x * i0)));
    RE[j].y = fmaf( mA.y, i1, fmaf(mA.x, r1, fmaf(-mA.w, i0, -mA.z * r0)));
    IM[j].y = fmaf(-mA.y, r1, fmaf(mA.x, i1, fmaf( mA.w, r0, -mA.z * i0)));
  }
}
template <int GPOS, int LM>
__device__ __forceinline__ void cnot_LL(v2f (&RE)[8], v2f (&IM)[8], int g) {
  if constexpr (GPOS >= 2) {
    constexpr int BANK = (GPOS == 3) ? 0xC : 0xA;
    if constexpr (LM == 4) {
#pragma unroll
      for (int j = 0; j < 8; ++j) {
        float t0 = dpp_mov<0x141>(RE[j].x);
        float t1 = dpp_mov<0x141>(RE[j].y);
        float t2 = dpp_mov<0x141>(IM[j].x);
        float t3 = dpp_mov<0x141>(IM[j].y);
        RE[j].x = mdpp<0x1B, 0xF, BANK>(RE[j].x, t0);
        RE[j].y = mdpp<0x1B, 0xF, BANK>(RE[j].y, t1);
        IM[j].x = mdpp<0x1B, 0xF, BANK>(IM[j].x, t2);
        IM[j].y = mdpp<0x1B, 0xF, BANK>(IM[j].y, t3);
      }
    } else {
      constexpr int CTRL = (LM == 1) ? 0xB1 : (LM == 2) ? 0x4E : 0x128;
#pragma unroll
      for (int j = 0; j < 8; ++j) {
        RE[j].x = mdpp<CTRL, 0xF, BANK>(RE[j].x, RE[j].x);
        RE[j].y = mdpp<CTRL, 0xF, BANK>(RE[j].y, RE[j].y);
        IM[j].x = mdpp<CTRL, 0xF, BANK>(IM[j].x, IM[j].x);
        IM[j].y = mdpp<CTRL, 0xF, BANK>(IM[j].y, IM[j].y);
      }
    }
  } else {
    constexpr int CTRL =
        (GPOS == 1 && LM == 1) ? 0xB4 :
        (GPOS == 1 && LM == 2) ? 0x44 :
        (GPOS == 0 && LM == 1) ? 0xA0 :
                                 0x6C;
#pragma unroll
    for (int j = 0; j < 8; ++j) {
      RE[j].x = dpp_mov<CTRL>(RE[j].x);
      RE[j].y = dpp_mov<CTRL>(RE[j].y);
      IM[j].x = dpp_mov<CTRL>(IM[j].x);
      IM[j].y = dpp_mov<CTRL>(IM[j].y);
    }
  }
}
template <int GPOS, int JM>
__device__ __forceinline__ void cnot_LR(v2f (&RE)[8], v2f (&IM)[8], int g) {
  const bool cb = (g >> GPOS) & 1;
#pragma unroll
  for (int j = 0; j < 8; ++j) {
    if (!(j & JM)) {
      const int j1 = j | JM;
      v2f r0 = RE[j], r1 = RE[j1];
      RE[j] = cb ? r1 : r0;  RE[j1] = cb ? r0 : r1;
      v2f i0 = IM[j], i1 = IM[j1];
      IM[j] = cb ? i1 : i0;  IM[j1] = cb ? i0 : i1;
    }
  }
}
template <int GPOS>
__device__ __forceinline__ void cnot_LH(v2f (&RE)[8], v2f (&IM)[8], int g) {
  const bool cb = (g >> GPOS) & 1;
#pragma unroll
  for (int j = 0; j < 8; ++j) {
    v2f r = RE[j]; v2f rs; rs.x = r.y; rs.y = r.x;
    RE[j] = cb ? rs : r;
    v2f i = IM[j]; v2f is2; is2.x = i.y; is2.y = i.x;
    IM[j] = cb ? is2 : i;
  }
}
template <int JC, int LM>
__device__ __forceinline__ void cnot_RL(v2f (&RE)[8], v2f (&IM)[8]) {
#pragma unroll
  for (int j = 0; j < 8; ++j) {
    if (j & JC) {
      RE[j] = dpp2<LM>(RE[j]);
      IM[j] = dpp2<LM>(IM[j]);
    }
  }
}
template <int JC>
__device__ __forceinline__ void cnot_RH(v2f (&RE)[8], v2f (&IM)[8]) {
#pragma unroll
  for (int j = 0; j < 8; ++j) {
    if (j & JC) {
      v2f r = RE[j]; RE[j].x = r.y; RE[j].y = r.x;
      v2f i = IM[j]; IM[j].x = i.y; IM[j].y = i.x;
    }
  }
}
template <int LM>
__device__ __forceinline__ void cnot_HL(v2f (&RE)[8], v2f (&IM)[8]) {
#pragma unroll
  for (int j = 0; j < 8; ++j) {
    RE[j].y = lane_xor<LM>(RE[j].y);
    IM[j].y = lane_xor<LM>(IM[j].y);
  }
}
template <int JC, int JT>
__device__ __forceinline__ void cnot_RR(v2f (&RE)[8], v2f (&IM)[8]) {
#pragma unroll
  for (int j = 0; j < 8; ++j) {
    if ((j & JC) && !(j & JT)) {
      const int j1 = j | JT;
      v2f t = RE[j]; RE[j] = RE[j1]; RE[j1] = t;
      t = IM[j]; IM[j] = IM[j1]; IM[j1] = t;
    }
  }
}

__device__ __forceinline__ void stage_fence() { __threadfence_block(); }

#define CIRCUIT_BODY(RE, IM, g)                                        \
  ROTS(0)                                                              \
  cnot_LL<3, 4>(RE, IM, g);  cnot_LL<2, 2>(RE, IM, g);                 \
  cnot_LL<1, 1>(RE, IM, g);  cnot_LR<0, 4>(RE, IM, g);                 \
  cnot_RR<4, 2>(RE, IM);     cnot_RR<2, 1>(RE, IM);                    \
  cnot_RH<1>(RE, IM);        cnot_HL<8>(RE, IM);                       \
  ROTS(1)                                                              \
  cnot_LL<3, 2>(RE, IM, g);  cnot_LL<2, 1>(RE, IM, g);                 \
  cnot_LR<1, 4>(RE, IM, g);  cnot_LR<0, 2>(RE, IM, g);                 \
  cnot_RR<4, 1>(RE, IM);     cnot_RH<2>(RE, IM);                       \
  cnot_RL<1, 8>(RE, IM);     cnot_HL<4>(RE, IM);                       \
  ROTS(2)                                                              \
  cnot_LL<3, 1>(RE, IM, g);  cnot_LR<2, 4>(RE, IM, g);                 \
  cnot_LR<1, 2>(RE, IM, g);  cnot_LR<0, 1>(RE, IM, g);                 \
  cnot_RH<4>(RE, IM);        cnot_RL<2, 8>(RE, IM);                    \
  cnot_RL<1, 4>(RE, IM);     cnot_HL<2>(RE, IM);                       \
  ROTS(3)                                                              \
  cnot_LR<3, 4>(RE, IM, g);  cnot_LR<2, 2>(RE, IM, g);                 \
  cnot_LR<1, 1>(RE, IM, g);  cnot_LH<0>(RE, IM, g);                    \
  cnot_RL<4, 8>(RE, IM);     cnot_RL<2, 4>(RE, IM);                    \
  cnot_RL<1, 2>(RE, IM);     cnot_HL<1>(RE, IM);

// ===========================================================================
// Kernel 1: build U columns -> Btf in MFMA-fragment order (256 KiB).
// ===========================================================================
__global__ __launch_bounds__(256) void build_u_kernel(
    const float* __restrict__ qw, _Float16* __restrict__ Btf) {
  __shared__ __align__(16) float rotm[32][4];
  const int tid = threadIdx.x;
  const int g = tid & 15;
  const int ls = tid >> 4;
  const int c = blockIdx.x * 16 + ls;  // input basis column = GEMM k

  if (tid < 32) {
    float phi = qw[tid * 3 + 0];
    float th  = qw[tid * 3 + 1];
    float om  = qw[tid * 3 + 2];
    float st_, ct; sincosf(0.5f * th, &st_, &ct);
    float sa, ca;  sincosf(0.5f * (phi + om), &sa, &ca);
    float sb, cb;  sincosf(0.5f * (phi - om), &sb, &cb);
    rotm[tid][0] =  ca * ct;
    rotm[tid][1] = -sa * ct;
    rotm[tid][2] = -cb * st_;
    rotm[tid][3] = -sb * st_;
  }
  __syncthreads();

  v2f RE[8], IM[8];
#pragma unroll
  for (int j = 0; j < 8; ++j) {
    RE[j].x = (c == g * 16 + 2 * j)     ? 1.0f : 0.0f;
    RE[j].y = (c == g * 16 + 2 * j + 1) ? 1.0f : 0.0f;
    IM[j] = sp(0.0f);
  }

#define RM(L, W) (*(const float4*)(&rotm[(L) * 8 + (W)][0]))
#define ROTS(L)                                                          \
  {                                                                      \
    float4 c0 = RM(L, 0), c1 = RM(L, 1), c2 = RM(L, 2), c3 = RM(L, 3),   \
           c4 = RM(L, 4), c5 = RM(L, 5), c6 = RM(L, 6), c7 = RM(L, 7);   \
    rot_lane<0>(RE, IM, c0, g);                                          \
    rot_lane<1>(RE, IM, c1, g);                                          \
    rot_lane<2>(RE, IM, c2, g);                                          \
    rot_lane<3>(RE, IM, c3, g);                                          \
    rot_regj<4>(RE, IM, c4);                                             \
    rot_regj<2>(RE, IM, c5);                                             \
    rot_regj<1>(RE, IM, c6);                                             \
    rot_regh(RE, IM, c7);                                                \
  }
  CIRCUIT_BODY(RE, IM, g)
#undef ROTS
#undef RM

  // fragment-order write: element (i = g*16+2j(+1), k = c)
  // p = g, cN = 2j(+1), kt = c>>5, rgrp = (c>>3)&3, e = c&7
  {
    const int kt = c >> 5;
    const int rg = (c >> 3) & 3;
    const int e  = c & 7;
    const int baseR = ((g * 2 + 0) * 8 + kt) * 512 + rg * 128 + e;
    const int baseI = ((g * 2 + 1) * 8 + kt) * 512 + rg * 128 + e;
#pragma unroll
    for (int j = 0; j < 8; ++j) {
      Btf[baseR + (2 * j) * 8]     = (_Float16)RE[j].x;
      Btf[baseR + (2 * j + 1) * 8] = (_Float16)RE[j].y;
      Btf[baseI + (2 * j) * 8]     = (_Float16)IM[j].x;
      Btf[baseI + (2 * j + 1) * 8] = (_Float16)IM[j].y;
    }
  }
}

// ===========================================================================
// Kernel 2: 256 threads (4 waves), 16 samples/block, 1024 blocks.
// ===========================================================================
__global__ __launch_bounds__(256) void hqc_main(
    const float* __restrict__ x,
    const float* __restrict__ w1, const float* __restrict__ b1,
    const float* __restrict__ w2, const float* __restrict__ b2,
    const float* __restrict__ w3, const float* __restrict__ b3,
    const _Float16* __restrict__ Btf,
    const float* __restrict__ wp1, const float* __restrict__ bp1,
    const float* __restrict__ wp2, const float* __restrict__ bp2,
    const float* __restrict__ wp3, const float* __restrict__ bp3,
    float* __restrict__ out, int B) {
  __shared__ __align__(16) _Float16 A_half[4096];  // psi fragment order, 8KB
  __shared__ __align__(16) float R1[16][44];  // x -> h2 -> z -> p2
  __shared__ __align__(16) float R2[16][68];  // h1 -> q -> p1

  const int tid = threadIdx.x;
  const int g = tid & 15;
  const int ls = tid >> 4;          // 0..15 sample slot
  const int s = blockIdx.x * 16 + ls;
  const bool valid = (s < B);

  // --- stage x -> R1 ---
  if (valid) {
    R1[ls][g]      = x[s * 41 + g];
    R1[ls][g + 16] = x[s * 41 + g + 16];
    if (g < 9) R1[ls][g + 32] = x[s * 41 + g + 32];
  }
  stage_fence();

  // --- pre layer1: 41 -> 64 (packed) -> R2 ---
  {
    const float4* w1v = (const float4*)w1;
    float4 bv = ((const float4*)b1)[g];
    v2f aA; aA.x = bv.x; aA.y = bv.y;
    v2f aB; aB.x = bv.z; aB.y = bv.w;
#pragma unroll 8
    for (int k = 0; k < 41; ++k) {
      float xk = R1[ls][k];
      float4 wv = w1v[k * 16 + g];
      v2f w01; w01.x = wv.x; w01.y = wv.y;
      v2f w23; w23.x = wv.z; w23.y = wv.w;
      v2f xv = sp(xk);
      aA = pkfma(xv, w01, aA);
      aB = pkfma(xv, w23, aB);
    }
    float4 st4;
    st4.x = fmaxf(aA.x, 0.f); st4.y = fmaxf(aA.y, 0.f);
    st4.z = fmaxf(aB.x, 0.f); st4.w = fmaxf(aB.y, 0.f);
    *(float4*)(&R2[ls][4 * g]) = st4;
  }
  stage_fence();

  // --- layer2: 64 -> 32 (packed) -> R1 ---
  {
    const v2f* w2v = (const v2f*)w2;
    v2f a2 = ((const v2f*)b2)[g];
#pragma unroll 8
    for (int k = 0; k < 64; ++k)
      a2 = pkfma(sp(R2[ls][k]), w2v[k * 16 + g], a2);
    R1[ls][2 * g]     = fmaxf(a2.x, 0.f);
    R1[ls][2 * g + 1] = fmaxf(a2.y, 0.f);
  }
  stage_fence();

  // --- layer3: 32 -> 8, tanh, RY -> R2 ---
  if (g < 8) {
    float acc = b3[g];
#pragma unroll
    for (int k = 0; k < 32; ++k) acc = fmaf(R1[ls][k], w3[k * 8 + g], acc);
    float q = tanhf(acc);
    float sh, ch; sincosf(q * PI_HALF, &sh, &ch);
    R2[ls][g]     = ch;
    R2[ls][8 + g] = sh;
  }
  stage_fence();

  // --- psi_in (real) -> A_half in fragment order ---
  {
    float cwv[8], swv[8];
#pragma unroll
    for (int w = 0; w < 8; ++w) { cwv[w] = R2[ls][w]; swv[w] = R2[ls][8 + w]; }
    float lp = 1.0f;
#pragma unroll
    for (int w = 0; w < 4; ++w) lp *= ((g >> (3 - w)) & 1) ? swv[w] : cwv[w];
    float f45[4];
#pragma unroll
    for (int a = 0; a < 4; ++a)
      f45[a] = ((a & 2) ? swv[4] : cwv[4]) * ((a & 1) ? swv[5] : cwv[5]);
    v2f F67[2];
    F67[0].x = cwv[6] * cwv[7]; F67[0].y = cwv[6] * swv[7];
    F67[1].x = swv[6] * cwv[7]; F67[1].y = swv[6] * swv[7];
#pragma unroll
    for (int j = 0; j < 8; ++j) {
      v2f amp = sp(lp * f45[j >> 1]) * F67[j & 1];
      h2v pk; pk.x = (_Float16)amp.x; pk.y = (_Float16)amp.y;
      // element (sample=ls, k=g*16+2j): addr=(kt*4+rgrp)*128 + ls*8 + e
      const int k = g * 16 + 2 * j;
      const int addr = ((k >> 5) * 4 + ((k >> 3) & 3)) * 128 + ls * 8 + (k & 7);
      *(h2v*)(&A_half[addr]) = pk;
    }
  }
  __syncthreads();

  // --- MFMA phase: kt-outer, 8 independent acc chains, coalesced B ---
  {
    const int l = tid & 63;
    const int w = tid >> 6;        // wave = pgrp 0..3

    f4 accr[4], acci[4];
#pragma unroll
    for (int t = 0; t < 4; ++t) {
      accr[t] = (f4){0.f, 0.f, 0.f, 0.f};
      acci[t] = (f4){0.f, 0.f, 0.f, 0.f};
    }
    const _Float16* Arow = &A_half[l * 8];
    const _Float16* Bre[4];
    const _Float16* Bim[4];
#pragma unroll
    for (int t = 0; t < 4; ++t) {
      const int p = w + 4 * t;
      Bre[t] = Btf + ((p * 2 + 0) * 8) * 512 + l * 8;
      Bim[t] = Btf + ((p * 2 + 1) * 8) * 512 + l * 8;
    }

#pragma unroll
    for (int kt = 0; kt < 8; ++kt) {
      h8 av = *(const h8*)(Arow + kt * 512);
      h8 br0 = *(const h8*)(Bre[0] + kt * 512);
      h8 bi0 = *(const h8*)(Bim[0] + kt * 512);
      h8 br1 = *(const h8*)(Bre[1] + kt * 512);
      h8 bi1 = *(const h8*)(Bim[1] + kt * 512);
      h8 br2 = *(const h8*)(Bre[2] + kt * 512);
      h8 bi2 = *(const h8*)(Bim[2] + kt * 512);
      h8 br3 = *(const h8*)(Bre[3] + kt * 512);
      h8 bi3 = *(const h8*)(Bim[3] + kt * 512);
      accr[0] = __builtin_amdgcn_mfma_f32_16x16x32_f16(av, br0, accr[0], 0, 0, 0);
      acci[0] = __builtin_amdgcn_mfma_f32_16x16x32_f16(av, bi0, acci[0], 0, 0, 0);
      accr[1] = __builtin_amdgcn_mfma_f32_16x16x32_f16(av, br1, accr[1], 0, 0, 0);
      acci[1] = __builtin_amdgcn_mfma_f32_16x16x32_f16(av, bi1, acci[1], 0, 0, 0);
      accr[2] = __builtin_amdgcn_mfma_f32_16x16x32_f16(av, br2, accr[2], 0, 0, 0);
      acci[2] = __builtin_amdgcn_mfma_f32_16x16x32_f16(av, bi2, acci[2], 0, 0, 0);
      accr[3] = __builtin_amdgcn_mfma_f32_16x16x32_f16(av, br3, accr[3], 0, 0, 0);
      acci[3] = __builtin_amdgcn_mfma_f32_16x16x32_f16(av, bi3, acci[3], 0, 0, 0);
    }

    // z-epilogue: zlo = wires 0-3 (p-tile bits), zhi = wires 4-7 (cN bits)
    const int cN = l & 15;
    const int rgrp = l >> 4;
    float4 zlo[4], zhi[4];
#pragma unroll
    for (int v = 0; v < 4; ++v) {
      zlo[v] = make_float4(0.f, 0.f, 0.f, 0.f);
      zhi[v] = make_float4(0.f, 0.f, 0.f, 0.f);
    }
    const float4 csgn = make_float4((cN & 8) ? -1.f : 1.f, (cN & 4) ? -1.f : 1.f,
                                    (cN & 2) ? -1.f : 1.f, (cN & 1) ? -1.f : 1.f);
#pragma unroll
    for (int t = 0; t < 4; ++t) {
      const int p = w + 4 * t;
      const float4 psgn = make_float4((p & 8) ? -1.f : 1.f, (p & 4) ? -1.f : 1.f,
                                      (p & 2) ? -1.f : 1.f, (p & 1) ? -1.f : 1.f);
#pragma unroll
      for (int v = 0; v < 4; ++v) {
        float tot = fmaf(accr[t][v], accr[t][v], acci[t][v] * acci[t][v]);
        zlo[v].x = fmaf(tot, psgn.x, zlo[v].x);
        zlo[v].y = fmaf(tot, psgn.y, zlo[v].y);
        zlo[v].z = fmaf(tot, psgn.z, zlo[v].z);
        zlo[v].w = fmaf(tot, psgn.w, zlo[v].w);
        zhi[v].x = fmaf(tot, csgn.x, zhi[v].x);
        zhi[v].y = fmaf(tot, csgn.y, zhi[v].y);
        zhi[v].z = fmaf(tot, csgn.z, zhi[v].z);
        zhi[v].w = fmaf(tot, csgn.w, zhi[v].w);
      }
    }

#define RED(M)                                                            \
  _Pragma("unroll")                                                       \
  for (int v = 0; v < 4; ++v) {                                           \
    zlo[v].x += lane_xor<M>(zlo[v].x); zlo[v].y += lane_xor<M>(zlo[v].y); \
    zlo[v].z += lane_xor<M>(zlo[v].z); zlo[v].w += lane_xor<M>(zlo[v].w); \
    zhi[v].x += lane_xor<M>(zhi[v].x); zhi[v].y += lane_xor<M>(zhi[v].y); \
    zhi[v].z += lane_xor<M>(zhi[v].z); zhi[v].w += lane_xor<M>(zhi[v].w); \
  }
    RED(1) RED(2) RED(4) RED(8)
#undef RED

    if (cN == 0) {
#pragma unroll
      for (int v = 0; v < 4; ++v) {
        const int smp = rgrp * 4 + v;
        *(float4*)&R1[smp][w * 8]     = zlo[v];
        *(float4*)&R1[smp][w * 8 + 4] = zhi[v];
      }
    }
  }
  __syncthreads();

  // --- post-MLP ---
  float zp[8];
#pragma unroll
  for (int k = 0; k < 8; ++k)
    zp[k] = (R1[ls][k] + R1[ls][8 + k]) + (R1[ls][16 + k] + R1[ls][24 + k]);

  {
    const v2f* wp1v = (const v2f*)wp1;
    v2f q1 = ((const v2f*)bp1)[g];
#pragma unroll
    for (int k = 0; k < 8; ++k)
      q1 = pkfma(sp(zp[k]), wp1v[k * 16 + g], q1);
    R2[ls][2 * g]     = fmaxf(q1.x, 0.f);
    R2[ls][2 * g + 1] = fmaxf(q1.y, 0.f);
  }
  stage_fence();

  {
    float q2 = bp2[g];
#pragma unroll
    for (int k = 0; k < 32; ++k) q2 = fmaf(R2[ls][k], wp2[k * 16 + g], q2);
    R1[ls][g] = fmaxf(q2, 0.f);
  }
  stage_fence();

  if (g < 5 && valid) {
    float o = bp3[g];
#pragma unroll
    for (int k = 0; k < 16; ++k) o = fmaf(R1[ls][k], wp3[k * 5 + g], o);
    out[s * 5 + g] = o;
  }
}

extern "C" void kernel_launch(void* const* d_in, const int* in_sizes, int n_in,
                              void* d_out, int out_size, void* d_ws,
                              size_t ws_size, hipStream_t stream) {
  const float* x   = (const float*)d_in[0];
  const float* w1  = (const float*)d_in[1];
  const float* b1  = (const float*)d_in[2];
  const float* w2  = (const float*)d_in[3];
  const float* b2  = (const float*)d_in[4];
  const float* w3  = (const float*)d_in[5];
  const float* b3  = (const float*)d_in[6];
  const float* qw  = (const float*)d_in[7];
  const float* wp1 = (const float*)d_in[8];
  const float* bp1 = (const float*)d_in[9];
  const float* wp2 = (const float*)d_in[10];
  const float* bp2 = (const float*)d_in[11];
  const float* wp3 = (const float*)d_in[12];
  const float* bp3 = (const float*)d_in[13];
  float* out = (float*)d_out;
  _Float16* Btf = (_Float16*)d_ws;  // 256 KiB
  const int B = in_sizes[0] / 41;

  hipLaunchKernelGGL(build_u_kernel, dim3(16), dim3(256), 0, stream, qw, Btf);

  const int blocks = (B + 15) / 16;
  hipLaunchKernelGGL(hqc_main, dim3(blocks), dim3(256), 0, stream,
                     x, w1, b1, w2, b2, w3, b3, Btf,
                     wp1, bp1, wp2, bp2, wp3, bp3, out, B);
}